// Round 13
// baseline (305.548 us; speedup 1.0000x reference)
//
#include <hip/hip_runtime.h>
#include <math.h>

#define NEGINF (-INFINITY)

typedef float fvec4 __attribute__((ext_vector_type(4)));

template <int M>
__device__ __forceinline__ float qbcast(float v) {
    // DPP quad_perm broadcast of lane M within each 4-lane quad (VALU, no LDS)
    return __int_as_float(
        __builtin_amdgcn_update_dpp(0, __float_as_int(v), M * 0x55, 0xF, 0xF, true));
}
__device__ __forceinline__ float fsigmoid(float z) { return 1.f / (1.f + __expf(-z)); }
__device__ __forceinline__ float ftanh(float z) {
    z = fminf(fmaxf(z, -20.f), 20.f);
    float e = __expf(2.f * z);
    return (e - 1.f) / (e + 1.f);
}

// ---------------- Kernel 1: per-image SPP + prep (2048 blocks x 448) ----------------
// Round-12 stream + ONE change: no barriers between the 3 channel planes.
// All 3 planes accumulate into registers (aT[3]/aB[3]); plane c+1's loads issue
// while plane c's fmaxes retire (removes 2 vmcnt-drain bubbles per block).
// One combined 12-value butterfly + single LDS reduce at block end.
__global__ __launch_bounds__(448, 7) void spp_prep_kernel(
    const float* __restrict__ frames, const float* __restrict__ Wf,
    const float* __restrict__ bf, const float* __restrict__ We,
    const float* __restrict__ be, float* __restrict__ out_pooled,
    float* __restrict__ out_fc, float* __restrict__ emb,
    float* __restrict__ femb) {
    int bid = blockIdx.x;
    int n = (bid & 7) * 256 + (bid >> 3);  // XCD-bijective swizzle (2048 = 8*256)
    int tid = threadIdx.x;
    const fvec4* __restrict__ base =
        reinterpret_cast<const fvec4*>(frames) + (size_t)n * 37632;  // 3*224*56
    int cc = tid % 56;
    bool left = cc < 28;

    float aT[3], aB[3];
#pragma unroll
    for (int c = 0; c < 3; ++c) {
        const fvec4* __restrict__ p = base + c * 12544 + tid;
        float t = NEGINF, bm = NEGINF;
#pragma unroll 7
        for (int r = 0; r < 14; ++r) {       // rows 0..111
            fvec4 f = __builtin_nontemporal_load(&p[r * 448]);
            t = fmaxf(t, fmaxf(fmaxf(f.x, f.y), fmaxf(f.z, f.w)));
        }
#pragma unroll 7
        for (int r = 14; r < 28; ++r) {      // rows 112..223
            fvec4 f = __builtin_nontemporal_load(&p[r * 448]);
            bm = fmaxf(bm, fmaxf(fmaxf(f.x, f.y), fmaxf(f.z, f.w)));
        }
        aT[c] = t; aB[c] = bm;
    }

    // combined butterfly over all 12 quadrant values
    float q[12];
#pragma unroll
    for (int c = 0; c < 3; ++c) {
        q[c * 4 + 0] = left ? aT[c] : NEGINF;
        q[c * 4 + 1] = left ? NEGINF : aT[c];
        q[c * 4 + 2] = left ? aB[c] : NEGINF;
        q[c * 4 + 3] = left ? NEGINF : aB[c];
    }
#pragma unroll
    for (int m = 32; m >= 1; m >>= 1) {
#pragma unroll
        for (int i = 0; i < 12; ++i) q[i] = fmaxf(q[i], __shfl_xor(q[i], m, 64));
    }
    __shared__ float sred[7][12];
    __shared__ float sp[15], sfc[15];
    int w = tid >> 6;
    if ((tid & 63) == 0) {
#pragma unroll
        for (int i = 0; i < 12; ++i) sred[w][i] = q[i];
    }
    __syncthreads();
    if (tid < 12) {
        float v = sred[0][tid];
#pragma unroll
        for (int ww = 1; ww < 7; ++ww) v = fmaxf(v, sred[ww][tid]);
        sp[tid] = v;
    } else if (tid < 15) {
        int c = tid - 12;
        float v = NEGINF;
#pragma unroll
        for (int ww = 0; ww < 7; ++ww)
#pragma unroll
            for (int i = 0; i < 4; ++i) v = fmaxf(v, sred[ww][c * 4 + i]);
        sp[tid] = v;
    }
    __syncthreads();
    if (tid < 15) {
        float a = bf[tid];
#pragma unroll
        for (int kk = 0; kk < 15; ++kk) a += sp[kk] * Wf[tid * 15 + kk];
        sfc[tid] = a;
        out_pooled[n * 15 + tid] = sp[tid];
        out_fc[n * 15 + tid] = a;
    }
    __syncthreads();
    if (tid < 8) {
        float a = be[tid], a2 = be[tid];
#pragma unroll
        for (int kk = 0; kk < 15; ++kk) {
            a  += sp[kk]  * We[tid * 15 + kk];
            a2 += sfc[kk] * We[tid * 15 + kk];
        }
        emb[n * 8 + tid]  = a;
        femb[n * 8 + tid] = a2;
    }
}

// ---------------- Kernel 2: per-batch LSTM (16 blocks x 64) ----------------
// Block b = batch b: stage its 8.25 KB of emb/femb to LDS (64 lanes, parallel
// across 16 CUs), then lanes 0..3 run the 128-step double-cell chain.
__device__ __forceinline__ float dot8(const float4& a, const float4& b,
                                      const float* __restrict__ w) {
    return a.x * w[0] + a.y * w[1] + a.z * w[2] + a.w * w[3] +
           b.x * w[4] + b.y * w[5] + b.z * w[6] + b.w * w[7];
}

__global__ __launch_bounds__(64) void lstm_kernel(
    const float* __restrict__ emb, const float* __restrict__ femb,
    const float* __restrict__ Wih, const float* __restrict__ Whh,
    const float* __restrict__ bih, const float* __restrict__ bhh,
    const float* __restrict__ Wp, const float* __restrict__ bp,
    float* __restrict__ prog, float* __restrict__ fprog) {
    __shared__ float le[1032], lf[1032];   // 128*8 + 8 pad (prefetch overread at s=127)
    int tid = threadIdx.x;
    int b = blockIdx.x;                    // batch 0..15

    // stage this batch's emb/femb (256 float4 each)
    const fvec4* ge = reinterpret_cast<const fvec4*>(emb)  + b * 256;
    const fvec4* gf = reinterpret_cast<const fvec4*>(femb) + b * 256;
#pragma unroll
    for (int it = 0; it < 4; ++it) {
        int g = it * 64 + tid;             // 0..255
        *reinterpret_cast<fvec4*>(&le[g * 4]) = ge[g];
        *reinterpret_cast<fvec4*>(&lf[g * 4]) = gf[g];
    }
    __syncthreads();
    if (tid >= 4) return;

    int k = tid;                           // hidden lane 0..3
    float wih[4][8], whh[4][4], bsum[4];
#pragma unroll
    for (int g = 0; g < 4; g++) {
        int row = g * 4 + k;
#pragma unroll
        for (int m = 0; m < 8; m++) wih[g][m] = Wih[row * 8 + m];
#pragma unroll
        for (int m = 0; m < 4; m++) whh[g][m] = Whh[row * 4 + m];
        bsum[g] = bih[row] + bhh[row];
    }
    float wpv[4];
#pragma unroll
    for (int m = 0; m < 4; m++) wpv[m] = Wp[m];
    float bpv = bp[0];

    // x-dots for step 0 (carry-independent part of the gates)
    float xd1[4], xd2[4];
    {
        float4 a0 = *(const float4*)(le);
        float4 a1 = *(const float4*)(le + 4);
        float4 f0 = *(const float4*)(lf);
        float4 f1 = *(const float4*)(lf + 4);
#pragma unroll
        for (int g = 0; g < 4; g++) {
            xd1[g] = bsum[g] + dot8(a0, a1, wih[g]);
            xd2[g] = bsum[g] + dot8(f0, f1, wih[g]);
        }
    }

    float h0 = 0.f, h1r = 0.f, h2r = 0.f, h3r = 0.f;
    float ck = 0.f;

    for (int s2 = 0; s2 < 128; ++s2) {
        // prefetch next step's x (s2=127 reads the pad region: harmless, unused)
        float4 na0 = *(const float4*)(le + (s2 + 1) * 8);
        float4 na1 = *(const float4*)(le + (s2 + 1) * 8 + 4);
        float4 nf0 = *(const float4*)(lf + (s2 + 1) * 8);
        float4 nf1 = *(const float4*)(lf + (s2 + 1) * 8 + 4);

        // ---- cell 1 ----
        float g0 = xd1[0] + h0 * whh[0][0] + h1r * whh[0][1] + h2r * whh[0][2] + h3r * whh[0][3];
        float g1 = xd1[1] + h0 * whh[1][0] + h1r * whh[1][1] + h2r * whh[1][2] + h3r * whh[1][3];
        float g2 = xd1[2] + h0 * whh[2][0] + h1r * whh[2][1] + h2r * whh[2][2] + h3r * whh[2][3];
        float g3 = xd1[3] + h0 * whh[3][0] + h1r * whh[3][1] + h2r * whh[3][2] + h3r * whh[3][3];
        float c1  = fsigmoid(g1) * ck + fsigmoid(g0) * ftanh(g2);
        float hk1 = fsigmoid(g3) * ftanh(c1);
        float b0 = qbcast<0>(hk1), b1 = qbcast<1>(hk1), b2 = qbcast<2>(hk1), b3 = qbcast<3>(hk1);
        float z = bpv + b0 * wpv[0] + b1 * wpv[1] + b2 * wpv[2] + b3 * wpv[3];
        if (k == 0) prog[b * 128 + s2] = fsigmoid(z);

        // ---- cell 2 (from h1, c1; its c is discarded) ----
        float e0 = xd2[0] + b0 * whh[0][0] + b1 * whh[0][1] + b2 * whh[0][2] + b3 * whh[0][3];
        float e1 = xd2[1] + b0 * whh[1][0] + b1 * whh[1][1] + b2 * whh[1][2] + b3 * whh[1][3];
        float e2 = xd2[2] + b0 * whh[2][0] + b1 * whh[2][1] + b2 * whh[2][2] + b3 * whh[2][3];
        float e3 = xd2[3] + b0 * whh[3][0] + b1 * whh[3][1] + b2 * whh[3][2] + b3 * whh[3][3];
        float c2v = fsigmoid(e1) * c1 + fsigmoid(e0) * ftanh(e2);
        float hk2 = fsigmoid(e3) * ftanh(c2v);
        float d0 = qbcast<0>(hk2), d1 = qbcast<1>(hk2), d2 = qbcast<2>(hk2), d3 = qbcast<3>(hk2);
        float z2 = bpv + d0 * wpv[0] + d1 * wpv[1] + d2 * wpv[2] + d3 * wpv[3];
        if (k == 0) fprog[b * 128 + s2] = fsigmoid(z2);

        // carry = (h1, c1)
        h0 = b0; h1r = b1; h2r = b2; h3r = b3; ck = c1;

        // next step's carry-independent x-dots (off the critical path)
#pragma unroll
        for (int g = 0; g < 4; g++) {
            xd1[g] = bsum[g] + dot8(na0, na1, wih[g]);
            xd2[g] = bsum[g] + dot8(nf0, nf1, wih[g]);
        }
    }
}

extern "C" void kernel_launch(void* const* d_in, const int* in_sizes, int n_in,
                              void* d_out, int out_size, void* d_ws, size_t ws_size,
                              hipStream_t stream) {
    const float* frames = (const float*)d_in[0];
    const float* Wf     = (const float*)d_in[1];
    const float* bf     = (const float*)d_in[2];
    const float* We     = (const float*)d_in[3];
    const float* be     = (const float*)d_in[4];
    const float* Wih    = (const float*)d_in[5];
    const float* Whh    = (const float*)d_in[6];
    const float* bih    = (const float*)d_in[7];
    const float* bhh    = (const float*)d_in[8];
    const float* Wp     = (const float*)d_in[9];
    const float* bp     = (const float*)d_in[10];

    float* out = (float*)d_out;
    float* out_prog   = out;                  // (16,128)
    float* out_fprog  = out + 2048;           // (16,128)
    float* out_pooled = out + 4096;           // (16,128,15)
    float* out_fc     = out + 4096 + 30720;   // (16,128,15)

    float* ws_f = (float*)d_ws;
    float* emb  = ws_f;                       // 2048*8 floats
    float* femb = ws_f + 16384;               // 2048*8 floats

    spp_prep_kernel<<<2048, 448, 0, stream>>>(frames, Wf, bf, We, be, out_pooled,
                                              out_fc, emb, femb);
    lstm_kernel<<<16, 64, 0, stream>>>(emb, femb, Wih, Whh, bih, bhh,
                                       Wp, bp, out_prog, out_fprog);
}

// Round 14
// 270.328 us; speedup vs baseline: 1.1303x; 1.1303x over previous
//
#include <hip/hip_runtime.h>
#include <math.h>

#define NEGINF (-INFINITY)

typedef float fvec4 __attribute__((ext_vector_type(4)));

template <int M>
__device__ __forceinline__ float qbcast(float v) {
    // DPP quad_perm broadcast of lane M within each 4-lane quad (VALU, no LDS)
    return __int_as_float(
        __builtin_amdgcn_update_dpp(0, __float_as_int(v), M * 0x55, 0xF, 0xF, true));
}
__device__ __forceinline__ float fsigmoid(float z) { return 1.f / (1.f + __expf(-z)); }
__device__ __forceinline__ float ftanh(float z) {
    z = fminf(fmaxf(z, -20.f), 20.f);
    float e = __expf(2.f * z);
    return (e - 1.f) / (e + 1.f);
}

// ---------------- Kernel 1: per-image SPP + prep (2048 blocks x 896) ----------------
// R12 logic, ONE geometry change: 896-thread blocks (14 waves), 2 blocks/CU
// -> 512 concurrent 602-KB sequential streams instead of 1024 (DRAM page
// locality test). rw=tid/56 in [0,16), cc=tid%56; iteration r reads float4 at
// r*896+tid (contiguous 14KB/iter); row = r*16+rw; top half <=> r<7.
__global__ __launch_bounds__(896, 7) void spp_prep_kernel(
    const float* __restrict__ frames, const float* __restrict__ Wf,
    const float* __restrict__ bf, const float* __restrict__ We,
    const float* __restrict__ be, float* __restrict__ out_pooled,
    float* __restrict__ out_fc, float* __restrict__ emb,
    float* __restrict__ femb) {
    int bid = blockIdx.x;
    int n = (bid & 7) * 256 + (bid >> 3);  // XCD-bijective swizzle (2048 = 8*256)
    int tid = threadIdx.x;
    const fvec4* __restrict__ base =
        reinterpret_cast<const fvec4*>(frames) + (size_t)n * 37632;  // 3*224*56
    int cc = tid % 56;
    bool left = cc < 28;

    __shared__ float sred[14][4];
    __shared__ float sq[3][4];
    __shared__ float sp[15], sfc[15];

    for (int c = 0; c < 3; ++c) {
        const fvec4* __restrict__ p = base + c * 12544 + tid;
        float aT = NEGINF, aB = NEGINF;
#pragma unroll 7
        for (int r = 0; r < 7; ++r) {        // rows 0..111
            fvec4 f = __builtin_nontemporal_load(&p[r * 896]);
            aT = fmaxf(aT, fmaxf(fmaxf(f.x, f.y), fmaxf(f.z, f.w)));
        }
#pragma unroll 7
        for (int r = 7; r < 14; ++r) {       // rows 112..223
            fvec4 f = __builtin_nontemporal_load(&p[r * 896]);
            aB = fmaxf(aB, fmaxf(fmaxf(f.x, f.y), fmaxf(f.z, f.w)));
        }
        float tl = left ? aT : NEGINF;
        float tr = left ? NEGINF : aT;
        float bl = left ? aB : NEGINF;
        float br = left ? NEGINF : aB;
#pragma unroll
        for (int m = 32; m >= 1; m >>= 1) {
            tl = fmaxf(tl, __shfl_xor(tl, m, 64));
            tr = fmaxf(tr, __shfl_xor(tr, m, 64));
            bl = fmaxf(bl, __shfl_xor(bl, m, 64));
            br = fmaxf(br, __shfl_xor(br, m, 64));
        }
        int w = tid >> 6;
        if ((tid & 63) == 0) { sred[w][0] = tl; sred[w][1] = tr; sred[w][2] = bl; sred[w][3] = br; }
        __syncthreads();
        if (tid < 4) {
            float v = sred[0][tid];
#pragma unroll
            for (int ww = 1; ww < 14; ++ww) v = fmaxf(v, sred[ww][tid]);
            sq[c][tid] = v;
        }
        __syncthreads();  // sred reused next channel
    }

    // ---- prep tail (amortized inside the stream) ----
    if (tid < 12) {
        sp[tid] = ((const float*)sq)[tid];  // sp[c*4+q] = sq[c][q]
    } else if (tid >= 16 && tid < 19) {
        int c = tid - 16;
        sp[12 + c] = fmaxf(fmaxf(sq[c][0], sq[c][1]), fmaxf(sq[c][2], sq[c][3]));
    }
    __syncthreads();
    if (tid < 15) {
        float a = bf[tid];
#pragma unroll
        for (int kk = 0; kk < 15; ++kk) a += sp[kk] * Wf[tid * 15 + kk];
        sfc[tid] = a;
        out_pooled[n * 15 + tid] = sp[tid];
        out_fc[n * 15 + tid] = a;
    }
    __syncthreads();
    if (tid < 8) {
        float a = be[tid], a2 = be[tid];
#pragma unroll
        for (int kk = 0; kk < 15; ++kk) {
            a  += sp[kk]  * We[tid * 15 + kk];
            a2 += sfc[kk] * We[tid * 15 + kk];
        }
        emb[n * 8 + tid]  = a;
        femb[n * 8 + tid] = a2;
    }
}

// ---------------- Kernel 2: LDS-staged double-cell LSTM (unchanged, round 12) ----------------
#define BSTRIDE 1036  // floats per batch in LDS: 128*8 + 12 pad

__device__ __forceinline__ float dot8(const float4& a, const float4& b,
                                      const float* __restrict__ w) {
    return a.x * w[0] + a.y * w[1] + a.z * w[2] + a.w * w[3] +
           b.x * w[4] + b.y * w[5] + b.z * w[6] + b.w * w[7];
}

__global__ __launch_bounds__(512, 1) void lstm_kernel(
    const float* __restrict__ emb, const float* __restrict__ femb,
    const float* __restrict__ Wih, const float* __restrict__ Whh,
    const float* __restrict__ bih, const float* __restrict__ bhh,
    const float* __restrict__ Wp, const float* __restrict__ bp,
    float* __restrict__ prog, float* __restrict__ fprog) {
    extern __shared__ float lds[];
    float* lemb  = lds;                  // [16][BSTRIDE]
    float* lfemb = lds + 16 * BSTRIDE;   // [16][BSTRIDE]
    int tid = threadIdx.x;

    // ---- Phase 0: bulk copy global -> LDS (4096 float4 per buffer) ----
    const fvec4* ge = reinterpret_cast<const fvec4*>(emb);
    const fvec4* gf = reinterpret_cast<const fvec4*>(femb);
#pragma unroll
    for (int it = 0; it < 8; ++it) {
        int g = it * 512 + tid;          // 0..4095
        int n = g >> 1;                  // image index
        int dst = (n >> 7) * BSTRIDE + (n & 127) * 8 + (g & 1) * 4;
        fvec4 ve = ge[g];
        fvec4 vf = gf[g];
        *reinterpret_cast<fvec4*>(&lemb[dst])  = ve;
        *reinterpret_cast<fvec4*>(&lfemb[dst]) = vf;
    }
    __syncthreads();

    // ---- Phase 1: double-cell LSTM, one wave (16 batches x 4 hidden lanes) ----
    if (tid >= 64) return;
    int b = tid >> 2, k = tid & 3;
    float wih[4][8], whh[4][4], bsum[4];
#pragma unroll
    for (int g = 0; g < 4; g++) {
        int row = g * 4 + k;
#pragma unroll
        for (int m = 0; m < 8; m++) wih[g][m] = Wih[row * 8 + m];
#pragma unroll
        for (int m = 0; m < 4; m++) whh[g][m] = Whh[row * 4 + m];
        bsum[g] = bih[row] + bhh[row];
    }
    float wpv[4];
#pragma unroll
    for (int m = 0; m < 4; m++) wpv[m] = Wp[m];
    float bpv = bp[0];

    const float* xe = lemb  + b * BSTRIDE;
    const float* xf = lfemb + b * BSTRIDE;

    // x-dots for step 0 (carry-independent part of the gates)
    float xd1[4], xd2[4];
    {
        float4 a0 = *(const float4*)(xe);
        float4 a1 = *(const float4*)(xe + 4);
        float4 f0 = *(const float4*)(xf);
        float4 f1 = *(const float4*)(xf + 4);
#pragma unroll
        for (int g = 0; g < 4; g++) {
            xd1[g] = bsum[g] + dot8(a0, a1, wih[g]);
            xd2[g] = bsum[g] + dot8(f0, f1, wih[g]);
        }
    }

    float h0 = 0.f, h1r = 0.f, h2r = 0.f, h3r = 0.f;
    float ck = 0.f;

    for (int s2 = 0; s2 < 128; ++s2) {
        // prefetch next step's x (s2=127 reads the pad region: harmless, unused)
        const float* nxe = xe + (s2 + 1) * 8;
        const float* nxf = xf + (s2 + 1) * 8;
        float4 na0 = *(const float4*)(nxe);
        float4 na1 = *(const float4*)(nxe + 4);
        float4 nf0 = *(const float4*)(nxf);
        float4 nf1 = *(const float4*)(nxf + 4);

        // ---- cell 1 ----
        float g0 = xd1[0] + h0 * whh[0][0] + h1r * whh[0][1] + h2r * whh[0][2] + h3r * whh[0][3];
        float g1 = xd1[1] + h0 * whh[1][0] + h1r * whh[1][1] + h2r * whh[1][2] + h3r * whh[1][3];
        float g2 = xd1[2] + h0 * whh[2][0] + h1r * whh[2][1] + h2r * whh[2][2] + h3r * whh[2][3];
        float g3 = xd1[3] + h0 * whh[3][0] + h1r * whh[3][1] + h2r * whh[3][2] + h3r * whh[3][3];
        float c1  = fsigmoid(g1) * ck + fsigmoid(g0) * ftanh(g2);
        float hk1 = fsigmoid(g3) * ftanh(c1);
        float b0 = qbcast<0>(hk1), b1 = qbcast<1>(hk1), b2 = qbcast<2>(hk1), b3 = qbcast<3>(hk1);
        float z = bpv + b0 * wpv[0] + b1 * wpv[1] + b2 * wpv[2] + b3 * wpv[3];
        if (k == 0) prog[b * 128 + s2] = fsigmoid(z);

        // ---- cell 2 (from h1, c1; its c is discarded) ----
        float e0 = xd2[0] + b0 * whh[0][0] + b1 * whh[0][1] + b2 * whh[0][2] + b3 * whh[0][3];
        float e1 = xd2[1] + b0 * whh[1][0] + b1 * whh[1][1] + b2 * whh[1][2] + b3 * whh[1][3];
        float e2 = xd2[2] + b0 * whh[2][0] + b1 * whh[2][1] + b2 * whh[2][2] + b3 * whh[2][3];
        float e3 = xd2[3] + b0 * whh[3][0] + b1 * whh[3][1] + b2 * whh[3][2] + b3 * whh[3][3];
        float c2v = fsigmoid(e1) * c1 + fsigmoid(e0) * ftanh(e2);
        float hk2 = fsigmoid(e3) * ftanh(c2v);
        float d0 = qbcast<0>(hk2), d1 = qbcast<1>(hk2), d2 = qbcast<2>(hk2), d3 = qbcast<3>(hk2);
        float z2 = bpv + d0 * wpv[0] + d1 * wpv[1] + d2 * wpv[2] + d3 * wpv[3];
        if (k == 0) fprog[b * 128 + s2] = fsigmoid(z2);

        // carry = (h1, c1)
        h0 = b0; h1r = b1; h2r = b2; h3r = b3; ck = c1;

        // next step's carry-independent x-dots (off the critical path)
#pragma unroll
        for (int g = 0; g < 4; g++) {
            xd1[g] = bsum[g] + dot8(na0, na1, wih[g]);
            xd2[g] = bsum[g] + dot8(nf0, nf1, wih[g]);
        }
    }
}

extern "C" void kernel_launch(void* const* d_in, const int* in_sizes, int n_in,
                              void* d_out, int out_size, void* d_ws, size_t ws_size,
                              hipStream_t stream) {
    const float* frames = (const float*)d_in[0];
    const float* Wf     = (const float*)d_in[1];
    const float* bf     = (const float*)d_in[2];
    const float* We     = (const float*)d_in[3];
    const float* be     = (const float*)d_in[4];
    const float* Wih    = (const float*)d_in[5];
    const float* Whh    = (const float*)d_in[6];
    const float* bih    = (const float*)d_in[7];
    const float* bhh    = (const float*)d_in[8];
    const float* Wp     = (const float*)d_in[9];
    const float* bp     = (const float*)d_in[10];

    float* out = (float*)d_out;
    float* out_prog   = out;                  // (16,128)
    float* out_fprog  = out + 2048;           // (16,128)
    float* out_pooled = out + 4096;           // (16,128,15)
    float* out_fc     = out + 4096 + 30720;   // (16,128,15)

    float* ws_f = (float*)d_ws;
    float* emb  = ws_f;                       // 2048*8 floats
    float* femb = ws_f + 16384;               // 2048*8 floats

    spp_prep_kernel<<<2048, 896, 0, stream>>>(frames, Wf, bf, We, be, out_pooled,
                                              out_fc, emb, femb);
    size_t lds_bytes = (size_t)2 * 16 * BSTRIDE * sizeof(float);  // 132,608 B
    lstm_kernel<<<1, 512, lds_bytes, stream>>>(emb, femb, Wih, Whh, bih, bhh,
                                               Wp, bp, out_prog, out_fprog);
}